// Round 6
// baseline (409.823 us; speedup 1.0000x reference)
//
#include <hip/hip_runtime.h>
#include <hip/hip_bf16.h>
#include <hip/hip_cooperative_groups.h>

namespace cg = cooperative_groups;

// Problem constants (B=2, T=4096, D=1024, H=512)
#define TT 4096
#define TD 1024
#define TM 8192            // B*T tokens
#define CN 3072            // big-GEMM N: [U 512 | Vn 512 | P 1024 | Y1 1024]
#define EPS 1e-5f

typedef __bf16 bf16;
typedef __bf16 bf16x4 __attribute__((ext_vector_type(4)));
typedef __bf16 bf16x8 __attribute__((ext_vector_type(8)));
typedef float  f32x4  __attribute__((ext_vector_type(4)));

#define GLOBAL_AS __attribute__((address_space(1)))
#define LDS_AS    __attribute__((address_space(3)))

// ===========================================================================
// Phase 1: prep — unit b in [0, 12304)
//  [0,16):    cvecP partials (sum over 256 e of wv_b[e]*merge_bot[e][j])
//  [16,8208): cast x f32 -> Xbf bf16
//  [8208+):   transposes w1_top/w1_bot/merge_top -> BigBT, merge_bot -> Amb,
//             cast wv_w -> WvBf
// ===========================================================================
__device__ __forceinline__ void prep_unit(int b, char* smem,
                                          const float* __restrict__ x,
                                          const float* __restrict__ w1,
                                          const float* __restrict__ wv_w,
                                          const float* __restrict__ wv_b,
                                          const float* __restrict__ merge_w,
                                          bf16* __restrict__ Xbf,
                                          bf16* __restrict__ BigBT,
                                          bf16* __restrict__ Amb,
                                          bf16* __restrict__ WvBf,
                                          float* __restrict__ cvecP) {
    const int tid = threadIdx.x;
    if (b < 16) {  // cvec partials: jb = b&3 (256 j's), ec = b>>2 (256 e's)
        const int j = (b & 3) * 256 + tid;
        const int e0 = (b >> 2) * 256;
        const float* col = merge_w + (size_t)(1024 + e0) * 1024 + j;
        float acc = 0.f;
#pragma unroll 32
        for (int e = 0; e < 256; ++e) acc += wv_b[e0 + e] * col[(size_t)e * 1024];
        cvecP[(b >> 2) * 1024 + j] = acc;
        return;
    }
    b -= 16;
    if (b < 8192) {  // cast x
        int i = b * 256 + tid;
        float4 v = ((const float4*)x)[i];
        bf16x4 o; o[0] = (bf16)v.x; o[1] = (bf16)v.y; o[2] = (bf16)v.z; o[3] = (bf16)v.w;
        *(bf16x4*)(Xbf + (size_t)i * 4) = o;
        return;
    }
    b -= 8192;
    if (b >= 3072) {  // cast wv_w
        int i = (b - 3072) * 256 + tid;
        float4 v = ((const float4*)wv_w)[i];
        bf16x4 o; o[0] = (bf16)v.x; o[1] = (bf16)v.y; o[2] = (bf16)v.z; o[3] = (bf16)v.w;
        *(bf16x4*)(WvBf + (size_t)i * 4) = o;
        return;
    }
    // 32x32 f32->bf16 transposes
    const float* src; bf16* dst; int srcN, tilesX, dstOff;
    if (b < 512)       {           src = w1;                        srcN = 512;  tilesX = 16; dst = BigBT; dstOff = 0;    }
    else if (b < 1024) { b -= 512; src = w1 + (size_t)1024 * 512;   srcN = 512;  tilesX = 16; dst = BigBT; dstOff = 512;  }
    else if (b < 2048) { b -= 1024; src = merge_w;                  srcN = 1024; tilesX = 32; dst = BigBT; dstOff = 2048; }
    else               { b -= 2048; src = merge_w + (size_t)1024 * 1024; srcN = 1024; tilesX = 32; dst = Amb; dstOff = 0; }
    float (*tile)[33] = (float(*)[33])smem;
    int n0 = (b % tilesX) * 32, k0 = (b / tilesX) * 32;
    int tx = tid & 31, ty = tid >> 5;
#pragma unroll
    for (int r = 0; r < 32; r += 8)
        tile[ty + r][tx] = src[(size_t)(k0 + ty + r) * srcN + n0 + tx];
    __syncthreads();
#pragma unroll
    for (int r = 0; r < 32; r += 8)
        dst[(size_t)(dstOff + n0 + ty + r) * 1024 + k0 + tx] = (bf16)tile[tx][ty + r];
    __syncthreads();   // protect smem reuse by the next grid-strided unit
}

// ===========================================================================
// Phase 2: wprime — unit b in [0,256): 64x64-tile GEMM
//   Wout[j][d] = sum_e Amb[j][e] * WvBf[d][e]   (M=N=K=1024)
// ===========================================================================
__device__ __forceinline__ void wprime_unit(int b, char* smem,
                                            const bf16* __restrict__ Amb,
                                            const bf16* __restrict__ WvBf,
                                            bf16* __restrict__ Wout) {
    bf16* As = (bf16*)smem;          // 64x64
    bf16* Bs = (bf16*)smem + 4096;   // 64x64
    const int m0 = (b >> 4) * 64;
    const int n0 = (b & 15) * 64;
    const int tid = threadIdx.x;
    const int wave = tid >> 6, lane = tid & 63;
    const int wr = (wave >> 1) * 32, wc = (wave & 1) * 32;
    const int lrow = lane & 15, cbase = lane >> 4;
    const int sw = lrow & 7;

    f32x4 acc[2][2] = {};

    for (int k0 = 0; k0 < 1024; k0 += 64) {
        __syncthreads();
#pragma unroll
        for (int c = 0; c < 2; ++c) {
            int e = (c * 256 + tid) * 8;
            int row = e >> 6;
            int q = (e >> 3) & 7;
            int gcol = ((q ^ (row & 7)) << 3);
            const bf16* ga = Amb  + (size_t)(m0 + row) * 1024 + k0 + gcol;
            const bf16* gb = WvBf + (size_t)(n0 + row) * 1024 + k0 + gcol;
            __builtin_amdgcn_global_load_lds((const GLOBAL_AS void*)ga,
                                             (LDS_AS void*)(As + e), 16, 0, 0);
            __builtin_amdgcn_global_load_lds((const GLOBAL_AS void*)gb,
                                             (LDS_AS void*)(Bs + e), 16, 0, 0);
        }
        __syncthreads();

#pragma unroll
        for (int kk = 0; kk < 2; ++kk) {
            const int qo = ((cbase + kk * 4) ^ sw) << 3;
            bf16x8 af[2], bfr[2];
#pragma unroll
            for (int i = 0; i < 2; ++i) {
                af[i]  = *(const bf16x8*)(As + (wr + i * 16 + lrow) * 64 + qo);
                bfr[i] = *(const bf16x8*)(Bs + (wc + i * 16 + lrow) * 64 + qo);
            }
#pragma unroll
            for (int i = 0; i < 2; ++i)
#pragma unroll
                for (int j = 0; j < 2; ++j)
                    acc[i][j] = __builtin_amdgcn_mfma_f32_16x16x32_bf16(af[i], bfr[j], acc[i][j], 0, 0, 0);
        }
    }
    __syncthreads();   // staging LDS reads done before any smem reuse

    const int lr = (lane >> 4) * 4, lc = lane & 15;
#pragma unroll
    for (int i = 0; i < 2; ++i)
#pragma unroll
        for (int j = 0; j < 2; ++j)
#pragma unroll
            for (int r = 0; r < 4; ++r)
                Wout[(size_t)(m0 + wr + i * 16 + lr + r) * 1024 + (n0 + wc + j * 16 + lc)]
                    = (bf16)acc[i][j][r];
}

// ===========================================================================
// Phase 3: big GEMM tile tb in [0,1024): C[8192][3072] = A[8192][1024] @ BT^T
// 256Mx96N block tile, wave = 64x96 (acc[4][6]), BK=64, XOR chunk swizzle,
// global_load_lds w=16, LDS-repack epilogue, XCD swizzle (verified r5:
// 890 TF, FETCH 57 MB, MfmaUtil 38%).
// ===========================================================================
__device__ __forceinline__ void gemm_tile(int tb, char* smem,
                                          const bf16* __restrict__ A,
                                          const bf16* __restrict__ BT,
                                          bf16* __restrict__ C) {
    bf16* As = (bf16*)smem;            // 256x64
    bf16* Bs = (bf16*)smem + 16384;    // 96x64
    const int NB = 3072, K = 1024;

    // XCD swizzle: same-XCD tiles share a 256-row y-stripe
    const int xcd = tb & 7, idx = tb >> 3;
    const int by = xcd * 4 + (idx >> 5);
    const int bx = idx & 31;
    const int m0 = by * 256;
    const int n0 = bx * 96;
    const int tid = threadIdx.x;
    const int wave = tid >> 6, lane = tid & 63;
    const int wr = wave * 64;
    const int lrow = lane & 15, cbase = lane >> 4;
    const int sw = lrow & 7;

    f32x4 acc[4][6] = {};

    for (int k0 = 0; k0 < K; k0 += 64) {
        __syncthreads();
#pragma unroll
        for (int c = 0; c < 11; ++c) {    // 8 A-chunks + 3 B-chunks
            if (c < 8) {
                int e = (c * 256 + tid) * 8;
                int row = e >> 6;
                int q = (e >> 3) & 7;
                int gcol = ((q ^ (row & 7)) << 3);
                const bf16* ga = A + (size_t)(m0 + row) * K + k0 + gcol;
                __builtin_amdgcn_global_load_lds((const GLOBAL_AS void*)ga,
                                                 (LDS_AS void*)(As + e), 16, 0, 0);
            } else {
                int e = ((c - 8) * 256 + tid) * 8;
                int row = e >> 6;
                int q = (e >> 3) & 7;
                int gcol = ((q ^ (row & 7)) << 3);
                const bf16* gb = BT + (size_t)(n0 + row) * K + k0 + gcol;
                __builtin_amdgcn_global_load_lds((const GLOBAL_AS void*)gb,
                                                 (LDS_AS void*)(Bs + e), 16, 0, 0);
            }
        }
        __syncthreads();

#pragma unroll
        for (int kk = 0; kk < 2; ++kk) {
            const int qo = ((cbase + kk * 4) ^ sw) << 3;
            bf16x8 af[4], bfr[6];
#pragma unroll
            for (int i = 0; i < 4; ++i)
                af[i] = *(const bf16x8*)(As + (wr + i * 16 + lrow) * 64 + qo);
#pragma unroll
            for (int j = 0; j < 6; ++j)
                bfr[j] = *(const bf16x8*)(Bs + (j * 16 + lrow) * 64 + qo);
#pragma unroll
            for (int i = 0; i < 4; ++i)
#pragma unroll
                for (int j = 0; j < 6; ++j)
                    acc[i][j] = __builtin_amdgcn_mfma_f32_16x16x32_bf16(af[i], bfr[j], acc[i][j], 0, 0, 0);
        }
    }

    // Epilogue: repack via LDS (wave-local, stride 104 bf16) -> b128 stores
    __syncthreads();
    bf16* ep = (bf16*)smem + wave * 6656;   // 64 rows x 104 stride
    const int lr = (lane >> 4) * 4, lc = lane & 15;
#pragma unroll
    for (int i = 0; i < 4; ++i)
#pragma unroll
        for (int j = 0; j < 6; ++j)
#pragma unroll
            for (int r = 0; r < 4; ++r)
                ep[(i * 16 + lr + r) * 104 + (j * 16 + lc)] = (bf16)acc[i][j][r];
    __syncthreads();

    bf16* Cw = C + (size_t)(m0 + wr) * NB + n0;
#pragma unroll
    for (int p = 0; p < 8; ++p) {           // cols 0..63
        int R = p * 8 + (lane >> 3);
        int Ccol = (lane & 7) * 8;
        bf16x8 v = *(const bf16x8*)(ep + R * 104 + Ccol);
        *(bf16x8*)(Cw + (size_t)R * NB + Ccol) = v;
    }
#pragma unroll
    for (int p = 0; p < 4; ++p) {           // cols 64..95
        int R = p * 16 + (lane >> 2);
        int Ccol = 64 + (lane & 3) * 8;
        bf16x8 v = *(const bf16x8*)(ep + R * 104 + Ccol);
        *(bf16x8*)(Cw + (size_t)R * NB + Ccol) = v;
    }
}

// ===========================================================================
// Phase 4: final — unit b in [0,2048): wave-per-token (4 tokens/unit),
// no __syncthreads. Sums cvecP's 4 partials inline.
// ===========================================================================
__device__ __forceinline__ void final_unit(int b,
                                           const bf16* __restrict__ C,
                                           const float* __restrict__ b1,
                                           const float* __restrict__ b2,
                                           const float* __restrict__ w2,
                                           const float* __restrict__ cvecP,
                                           const float* __restrict__ merge_b,
                                           const float* __restrict__ gamma,
                                           const float* __restrict__ beta,
                                           float* __restrict__ out) {
    const int wave = threadIdx.x >> 6, lane = threadIdx.x & 63;
    const int row = b * 4 + wave;
    const int t = row & (TT - 1);
    const bf16* Crow = C + (size_t)row * CN;

    const int h0 = lane * 8;
    bf16x8 u8 = *(const bf16x8*)(Crow + h0);
    float4 b1a = *(const float4*)(b1 + h0), b1b = *(const float4*)(b1 + h0 + 4);
    float4 w2a = *(const float4*)(w2 + h0), w2b = *(const float4*)(w2 + h0 + 4);
    float u[8] = {(float)u8[0] + b1a.x, (float)u8[1] + b1a.y,
                  (float)u8[2] + b1a.z, (float)u8[3] + b1a.w,
                  (float)u8[4] + b1b.x, (float)u8[5] + b1b.y,
                  (float)u8[6] + b1b.z, (float)u8[7] + b1b.w};
    const float w2v[8] = {w2a.x, w2a.y, w2a.z, w2a.w, w2b.x, w2b.y, w2b.z, w2b.w};

    float partial[4];
#pragma unroll
    for (int w = 0; w < 4; ++w) {
        float p = 0.f;
        if (t >= w + 1) {
            bf16x8 v8 = *(const bf16x8*)(C + (size_t)(row - w - 1) * CN + 512 + h0);
#pragma unroll
            for (int k = 0; k < 8; ++k) {
                float z = u[k] + (float)v8[k];
                p += (z / (1.f + __expf(-z))) * w2v[k];
            }
        } else {
#pragma unroll
            for (int k = 0; k < 8; ++k) {
                float z = u[k];
                p += (z / (1.f + __expf(-z))) * w2v[k];
            }
        }
        partial[w] = p;
    }
#pragma unroll
    for (int w = 0; w < 4; ++w)
#pragma unroll
        for (int off = 1; off < 64; off <<= 1)
            partial[w] += __shfl_xor(partial[w], off, 64);

    const float bias2 = b2[0];
    float taus[4];
#pragma unroll
    for (int w = 0; w < 4; ++w)
        taus[w] = 1.f / (1.f + __expf(-(partial[w] + bias2)));
    const float tsum = taus[0] + taus[1] + taus[2] + taus[3];

    const int d0 = lane * 16;
    bf16x8 y1a = *(const bf16x8*)(Crow + 2048 + d0);
    bf16x8 y1b = *(const bf16x8*)(Crow + 2048 + d0 + 8);
    float v[16];
#pragma unroll
    for (int k = 0; k < 8; ++k) { v[k] = (float)y1a[k]; v[8 + k] = (float)y1b[k]; }
#pragma unroll
    for (int q = 0; q < 4; ++q) {
        const int d = d0 + q * 4;
        float4 c0 = *(const float4*)(cvecP + d);
        float4 c1 = *(const float4*)(cvecP + 1024 + d);
        float4 c2 = *(const float4*)(cvecP + 2048 + d);
        float4 c3 = *(const float4*)(cvecP + 3072 + d);
        float4 mb = *(const float4*)(merge_b + d);
        v[q*4+0] += tsum * (c0.x + c1.x + c2.x + c3.x) + mb.x;
        v[q*4+1] += tsum * (c0.y + c1.y + c2.y + c3.y) + mb.y;
        v[q*4+2] += tsum * (c0.z + c1.z + c2.z + c3.z) + mb.z;
        v[q*4+3] += tsum * (c0.w + c1.w + c2.w + c3.w) + mb.w;
    }
#pragma unroll
    for (int w = 0; w < 4; ++w) {
        if (t >= w + 1) {
            const bf16* Pn = C + (size_t)(row - w - 1) * CN + 1024 + d0;
            bf16x8 pa = *(const bf16x8*)Pn;
            bf16x8 pb = *(const bf16x8*)(Pn + 8);
#pragma unroll
            for (int k = 0; k < 8; ++k) {
                v[k] += taus[w] * (float)pa[k];
                v[8 + k] += taus[w] * (float)pb[k];
            }
        }
    }

    float s = 0.f, ss = 0.f;
#pragma unroll
    for (int k = 0; k < 16; ++k) { s += v[k]; ss += v[k] * v[k]; }
#pragma unroll
    for (int off = 1; off < 64; off <<= 1) {
        s  += __shfl_xor(s, off, 64);
        ss += __shfl_xor(ss, off, 64);
    }
    const float mu = s * (1.f / TD);
    const float var = ss * (1.f / TD) - mu * mu;
    const float r = rsqrtf(var + EPS);

#pragma unroll
    for (int q = 0; q < 4; ++q) {
        const int d = d0 + q * 4;
        float4 g  = *(const float4*)(gamma + d);
        float4 bt = *(const float4*)(beta + d);
        float4 o;
        o.x = (v[q*4+0] - mu) * r * g.x + bt.x;
        o.y = (v[q*4+1] - mu) * r * g.y + bt.y;
        o.z = (v[q*4+2] - mu) * r * g.z + bt.z;
        o.w = (v[q*4+3] - mu) * r * g.w + bt.w;
        *(float4*)(out + (size_t)row * TD + d) = o;
    }
}

// ===========================================================================
// Mega kernel: ONE cooperative launch, 512 blocks (= exactly 2 blocks/CU at
// 57344 B LDS), phases separated by grid.sync().
// ===========================================================================
__global__ __launch_bounds__(256, 2) void mega_kernel(
        const float* x, const float* w1, const float* b1, const float* w2,
        const float* b2, const float* wv_w, const float* wv_b,
        const float* merge_w, const float* merge_b, const float* gamma,
        const float* beta, bf16* Xbf, bf16* BigBT, bf16* Amb, bf16* WvBf,
        float* cvecP, bf16* Cbuf, float* out) {
    cg::grid_group grid = cg::this_grid();
    __shared__ __align__(16) char smem[57344];

    for (int b = blockIdx.x; b < 12304; b += 512)
        prep_unit(b, smem, x, w1, wv_w, wv_b, merge_w, Xbf, BigBT, Amb, WvBf, cvecP);
    grid.sync();

    if (blockIdx.x < 256)
        wprime_unit(blockIdx.x, smem, Amb, WvBf, BigBT + (size_t)1024 * 1024);
    grid.sync();

    for (int tb = blockIdx.x; tb < 1024; tb += 512)
        gemm_tile(tb, smem, Xbf, BigBT, Cbuf);
    grid.sync();

    for (int b = blockIdx.x; b < 2048; b += 512)
        final_unit(b, Cbuf, b1, b2, w2, cvecP, merge_b, gamma, beta, out);
}

// ===========================================================================
// Fallback standalone kernels (r5-equivalent path) in case cooperative
// launch is rejected by the harness/driver.
// ===========================================================================
__global__ __launch_bounds__(256) void prep_kernel(
        const float* x, const float* w1, const float* wv_w, const float* wv_b,
        const float* merge_w, bf16* Xbf, bf16* BigBT, bf16* Amb, bf16* WvBf,
        float* cvecP) {
    __shared__ __align__(16) char smem[4224];
    prep_unit(blockIdx.x, smem, x, w1, wv_w, wv_b, merge_w, Xbf, BigBT, Amb, WvBf, cvecP);
}

__global__ __launch_bounds__(256) void wprime_kernel(
        const bf16* Amb, const bf16* WvBf, bf16* Wout) {
    __shared__ __align__(16) char smem[16384];
    wprime_unit(blockIdx.x, smem, Amb, WvBf, Wout);
}

__global__ __launch_bounds__(256, 2) void gemm_kernel(
        const bf16* A, const bf16* BT, bf16* C) {
    __shared__ __align__(16) char smem[57344];
    gemm_tile(blockIdx.x, smem, A, BT, C);
}

__global__ __launch_bounds__(256) void final_kernel(
        const bf16* C, const float* b1, const float* b2, const float* w2,
        const float* cvecP, const float* merge_b, const float* gamma,
        const float* beta, float* out) {
    final_unit(blockIdx.x, C, b1, b2, w2, cvecP, merge_b, gamma, beta, out);
}

// ---------------------------------------------------------------------------
extern "C" void kernel_launch(void* const* d_in, const int* in_sizes, int n_in,
                              void* d_out, int out_size, void* d_ws, size_t ws_size,
                              hipStream_t stream) {
    const float* x       = (const float*)d_in[0];
    const float* w1      = (const float*)d_in[1];
    const float* b1      = (const float*)d_in[2];
    const float* w2      = (const float*)d_in[3];
    const float* b2      = (const float*)d_in[4];
    const float* wv_w    = (const float*)d_in[5];
    const float* wv_b    = (const float*)d_in[6];
    const float* merge_w = (const float*)d_in[7];
    const float* merge_b = (const float*)d_in[8];
    const float* gamma   = (const float*)d_in[9];
    const float* beta    = (const float*)d_in[10];
    float* out = (float*)d_out;

    char* ws = (char*)d_ws;
    bf16*  Xbf   = (bf16*)ws;  ws += (size_t)TM * 1024 * 2;    // [8192][1024]
    bf16*  BigBT = (bf16*)ws;  ws += (size_t)CN * 1024 * 2;    // [3072 n][1024 k]
    bf16*  Amb   = (bf16*)ws;  ws += (size_t)1024 * 1024 * 2;  // merge_bot^T
    bf16*  WvBf  = (bf16*)ws;  ws += (size_t)1024 * 1024 * 2;  // wv_w bf16
    float* cvecP = (float*)ws; ws += (size_t)4 * 1024 * 4;     // cvec partials
    bf16*  Cbuf  = (bf16*)ws;                                  // [8192][3072]

    void* args[] = {(void*)&x, (void*)&w1, (void*)&b1, (void*)&w2, (void*)&b2,
                    (void*)&wv_w, (void*)&wv_b, (void*)&merge_w, (void*)&merge_b,
                    (void*)&gamma, (void*)&beta,
                    (void*)&Xbf, (void*)&BigBT, (void*)&Amb, (void*)&WvBf,
                    (void*)&cvecP, (void*)&Cbuf, (void*)&out};
    hipError_t err = hipLaunchCooperativeKernel((void*)mega_kernel,
                                                dim3(512), dim3(256),
                                                args, 0, stream);
    if (err != hipSuccess) {
        (void)hipGetLastError();   // clear; fall back to 4-launch pipeline
        prep_kernel<<<12304, 256, 0, stream>>>(x, w1, wv_w, wv_b, merge_w,
                                               Xbf, BigBT, Amb, WvBf, cvecP);
        wprime_kernel<<<256, 256, 0, stream>>>(Amb, WvBf, BigBT + (size_t)1024 * 1024);
        gemm_kernel<<<1024, 256, 0, stream>>>(Xbf, BigBT, Cbuf);
        final_kernel<<<2048, 256, 0, stream>>>(Cbuf, b1, b2, w2, cvecP, merge_b,
                                               gamma, beta, out);
    }
}

// Round 7
// 200.798 us; speedup vs baseline: 2.0410x; 2.0410x over previous
//
#include <hip/hip_runtime.h>
#include <hip/hip_bf16.h>

// Problem constants (B=2, T=4096, D=1024, H=512)
#define TT 4096
#define TD 1024
#define TM 8192            // B*T tokens
#define CN 3072            // big-GEMM N: [U 512 | Vn 512 | P 1024 | Y1 1024]
#define EPS 1e-5f

typedef __bf16 bf16;
typedef __bf16 bf16x4 __attribute__((ext_vector_type(4)));
typedef __bf16 bf16x8 __attribute__((ext_vector_type(8)));
typedef float  f32x4  __attribute__((ext_vector_type(4)));

#define GLOBAL_AS __attribute__((address_space(1)))
#define LDS_AS    __attribute__((address_space(3)))

// ===========================================================================
// Launch 1: weights-only prep. grid = 4096.
//  [0,512):     w1_top^T    -> BigBT rows    0..511
//  [512,1024):  w1_bot^T    -> BigBT rows  512..1023
//  [1024,2048): merge_top^T -> BigBT rows 2048..3071
//  [2048,3072): merge_bot^T -> Amb [j][e]
//  [3072,4096): cast wv_w f32 -> WvBf bf16
// ===========================================================================
__global__ __launch_bounds__(256) void prep_kernel(const float* __restrict__ w1,
                                                   const float* __restrict__ wv_w,
                                                   const float* __restrict__ merge_w,
                                                   bf16* __restrict__ BigBT,
                                                   bf16* __restrict__ Amb,
                                                   bf16* __restrict__ WvBf) {
    __shared__ float tile[32][33];
    int b = blockIdx.x;
    const int tid = threadIdx.x;

    if (b >= 3072) {  // cast wv_w
        int i = (b - 3072) * 256 + tid;
        float4 v = ((const float4*)wv_w)[i];
        bf16x4 o; o[0] = (bf16)v.x; o[1] = (bf16)v.y; o[2] = (bf16)v.z; o[3] = (bf16)v.w;
        *(bf16x4*)(WvBf + (size_t)i * 4) = o;
        return;
    }
    const float* src; bf16* dst; int srcN, tilesX, dstOff;
    if (b < 512)       {            src = w1;                        srcN = 512;  tilesX = 16; dst = BigBT; dstOff = 0;    }
    else if (b < 1024) { b -= 512;  src = w1 + (size_t)1024 * 512;   srcN = 512;  tilesX = 16; dst = BigBT; dstOff = 512;  }
    else if (b < 2048) { b -= 1024; src = merge_w;                   srcN = 1024; tilesX = 32; dst = BigBT; dstOff = 2048; }
    else               { b -= 2048; src = merge_w + (size_t)1024 * 1024; srcN = 1024; tilesX = 32; dst = Amb; dstOff = 0; }
    int n0 = (b % tilesX) * 32, k0 = (b / tilesX) * 32;
    int tx = tid & 31, ty = tid >> 5;
#pragma unroll
    for (int r = 0; r < 32; r += 8)
        tile[ty + r][tx] = src[(size_t)(k0 + ty + r) * srcN + n0 + tx];
    __syncthreads();
#pragma unroll
    for (int r = 0; r < 32; r += 8)
        dst[(size_t)(dstOff + n0 + ty + r) * 1024 + k0 + tx] = (bf16)tile[tx][ty + r];
}

// ===========================================================================
// Launch 2: aux — wprime GEMM tiles co-resident with memory-bound work so the
// MFMA-bound wprime hides under the x-cast stream. grid = 8464.
//  [0,256):      wprime 64x64 tile GEMM:  Wout[m][n] = sum_k Amb[m][k]*WvBf[n][k]
//  [256,8448):   cast x f32 -> Xbf bf16
//  [8448,8464):  cvecP partials: sum over 256 e of wv_b[e]*merge_bot[e][j]
// ===========================================================================
__global__ __launch_bounds__(256) void aux_kernel(const float* __restrict__ x,
                                                  const float* __restrict__ merge_w,
                                                  const float* __restrict__ wv_b,
                                                  const bf16* __restrict__ Amb,
                                                  const bf16* __restrict__ WvBf,
                                                  bf16* __restrict__ Wout,
                                                  bf16* __restrict__ Xbf,
                                                  float* __restrict__ cvecP) {
    __shared__ bf16 As[64 * 64];
    __shared__ bf16 Bs[64 * 64];
    int b = blockIdx.x;
    const int tid = threadIdx.x;

    if (b >= 8448) {  // cvecP partials: jb = (b-8448)&3, ec = (b-8448)>>2
        b -= 8448;
        const int j = (b & 3) * 256 + tid;
        const int e0 = (b >> 2) * 256;
        const float* col = merge_w + (size_t)(1024 + e0) * 1024 + j;
        float acc = 0.f;
#pragma unroll 32
        for (int e = 0; e < 256; ++e) acc += wv_b[e0 + e] * col[(size_t)e * 1024];
        cvecP[(b >> 2) * 1024 + j] = acc;
        return;
    }
    if (b >= 256) {   // cast x
        int i = (b - 256) * 256 + tid;
        float4 v = ((const float4*)x)[i];
        bf16x4 o; o[0] = (bf16)v.x; o[1] = (bf16)v.y; o[2] = (bf16)v.z; o[3] = (bf16)v.w;
        *(bf16x4*)(Xbf + (size_t)i * 4) = o;
        return;
    }
    // wprime 64x64 tile (verified r4-r6; BK=64, XOR chunk swizzle)
    const int m0 = (b >> 4) * 64;
    const int n0 = (b & 15) * 64;
    const int wave = tid >> 6, lane = tid & 63;
    const int wr = (wave >> 1) * 32, wc = (wave & 1) * 32;
    const int lrow = lane & 15, cbase = lane >> 4;
    const int sw = lrow & 7;

    f32x4 acc[2][2] = {};

    for (int k0 = 0; k0 < 1024; k0 += 64) {
        __syncthreads();
#pragma unroll
        for (int c = 0; c < 2; ++c) {
            int e = (c * 256 + tid) * 8;
            int row = e >> 6;
            int q = (e >> 3) & 7;
            int gcol = ((q ^ (row & 7)) << 3);
            const bf16* ga = Amb  + (size_t)(m0 + row) * 1024 + k0 + gcol;
            const bf16* gb = WvBf + (size_t)(n0 + row) * 1024 + k0 + gcol;
            __builtin_amdgcn_global_load_lds((const GLOBAL_AS void*)ga,
                                             (LDS_AS void*)(As + e), 16, 0, 0);
            __builtin_amdgcn_global_load_lds((const GLOBAL_AS void*)gb,
                                             (LDS_AS void*)(Bs + e), 16, 0, 0);
        }
        __syncthreads();

#pragma unroll
        for (int kk = 0; kk < 2; ++kk) {
            const int qo = ((cbase + kk * 4) ^ sw) << 3;
            bf16x8 af[2], bfr[2];
#pragma unroll
            for (int i = 0; i < 2; ++i) {
                af[i]  = *(const bf16x8*)(As + (wr + i * 16 + lrow) * 64 + qo);
                bfr[i] = *(const bf16x8*)(Bs + (wc + i * 16 + lrow) * 64 + qo);
            }
#pragma unroll
            for (int i = 0; i < 2; ++i)
#pragma unroll
                for (int j = 0; j < 2; ++j)
                    acc[i][j] = __builtin_amdgcn_mfma_f32_16x16x32_bf16(af[i], bfr[j], acc[i][j], 0, 0, 0);
        }
    }

    const int lr = (lane >> 4) * 4, lc = lane & 15;
#pragma unroll
    for (int i = 0; i < 2; ++i)
#pragma unroll
        for (int j = 0; j < 2; ++j)
#pragma unroll
            for (int r = 0; r < 4; ++r)
                Wout[(size_t)(m0 + wr + i * 16 + lr + r) * 1024 + (n0 + wc + j * 16 + lc)]
                    = (bf16)acc[i][j][r];
}

// ===========================================================================
// Launch 3: big GEMM. C[8192][3072] = Xbf @ BigBT^T. Unchanged from r5
// (890 TF: 256Mx96N tile, wave 64x96, BK=64, XOR swizzle, LDS-repack epi,
// XCD y-stripe swizzle). grid = 1024. Epilogue 2nd barrier dropped
// (repack region is wave-local; in-wave DS ordering suffices).
// ===========================================================================
__global__ __launch_bounds__(256, 2) void gemm_kernel(const bf16* __restrict__ A,
                                                      const bf16* __restrict__ BT,
                                                      bf16* __restrict__ C) {
    __shared__ bf16 SMEM[28672];          // 57344 B
    bf16* As = SMEM;                      // 256x64
    bf16* Bs = SMEM + 16384;              // 96x64
    const int NB = 3072, K = 1024;

    const int tb = blockIdx.x;
    const int xcd = tb & 7, idx = tb >> 3;
    const int by = xcd * 4 + (idx >> 5);
    const int bx = idx & 31;
    const int m0 = by * 256;
    const int n0 = bx * 96;
    const int tid = threadIdx.x;
    const int wave = tid >> 6, lane = tid & 63;
    const int wr = wave * 64;
    const int lrow = lane & 15, cbase = lane >> 4;
    const int sw = lrow & 7;

    f32x4 acc[4][6] = {};

    for (int k0 = 0; k0 < K; k0 += 64) {
        __syncthreads();
#pragma unroll
        for (int c = 0; c < 11; ++c) {    // 8 A-chunks + 3 B-chunks
            if (c < 8) {
                int e = (c * 256 + tid) * 8;
                int row = e >> 6;
                int q = (e >> 3) & 7;
                int gcol = ((q ^ (row & 7)) << 3);
                const bf16* ga = A + (size_t)(m0 + row) * K + k0 + gcol;
                __builtin_amdgcn_global_load_lds((const GLOBAL_AS void*)ga,
                                                 (LDS_AS void*)(As + e), 16, 0, 0);
            } else {
                int e = ((c - 8) * 256 + tid) * 8;
                int row = e >> 6;
                int q = (e >> 3) & 7;
                int gcol = ((q ^ (row & 7)) << 3);
                const bf16* gb = BT + (size_t)(n0 + row) * K + k0 + gcol;
                __builtin_amdgcn_global_load_lds((const GLOBAL_AS void*)gb,
                                                 (LDS_AS void*)(Bs + e), 16, 0, 0);
            }
        }
        __syncthreads();

#pragma unroll
        for (int kk = 0; kk < 2; ++kk) {
            const int qo = ((cbase + kk * 4) ^ sw) << 3;
            bf16x8 af[4], bfr[6];
#pragma unroll
            for (int i = 0; i < 4; ++i)
                af[i] = *(const bf16x8*)(As + (wr + i * 16 + lrow) * 64 + qo);
#pragma unroll
            for (int j = 0; j < 6; ++j)
                bfr[j] = *(const bf16x8*)(Bs + (j * 16 + lrow) * 64 + qo);
#pragma unroll
            for (int i = 0; i < 4; ++i)
#pragma unroll
                for (int j = 0; j < 6; ++j)
                    acc[i][j] = __builtin_amdgcn_mfma_f32_16x16x32_bf16(af[i], bfr[j], acc[i][j], 0, 0, 0);
        }
    }

    // Epilogue: repack via wave-local LDS (stride 104) -> b128 stores
    __syncthreads();                       // other waves' As/Bs reads done
    bf16* ep = SMEM + wave * 6656;         // 64 rows x 104 stride
    const int lr = (lane >> 4) * 4, lc = lane & 15;
#pragma unroll
    for (int i = 0; i < 4; ++i)
#pragma unroll
        for (int j = 0; j < 6; ++j)
#pragma unroll
            for (int r = 0; r < 4; ++r)
                ep[(i * 16 + lr + r) * 104 + (j * 16 + lc)] = (bf16)acc[i][j][r];
    // wave-local region: in-wave ds_write->ds_read ordering handled by lgkmcnt

    bf16* Cw = C + (size_t)(m0 + wr) * NB + n0;
#pragma unroll
    for (int p = 0; p < 8; ++p) {           // cols 0..63
        int R = p * 8 + (lane >> 3);
        int Ccol = (lane & 7) * 8;
        bf16x8 v = *(const bf16x8*)(ep + R * 104 + Ccol);
        *(bf16x8*)(Cw + (size_t)R * NB + Ccol) = v;
    }
#pragma unroll
    for (int p = 0; p < 4; ++p) {           // cols 64..95
        int R = p * 16 + (lane >> 2);
        int Ccol = 64 + (lane & 3) * 8;
        bf16x8 v = *(const bf16x8*)(ep + R * 104 + Ccol);
        *(bf16x8*)(Cw + (size_t)R * NB + Ccol) = v;
    }
}

// ===========================================================================
// Launch 4: final — wave-per-token, 4 tokens/block, no __syncthreads.
// XCD-contiguous token mapping: g=(b&7)*256+(b>>3) gives XCD x the token
// stripe [x*1024,(x+1)*1024) -> neighbor reads (t-1..t-4) hit own-XCD L2,
// and the stripe matches gemm's XCD write placement.
// ===========================================================================
__global__ __launch_bounds__(256) void final_kernel(const bf16* __restrict__ C,
                                                    const float* __restrict__ b1,
                                                    const float* __restrict__ b2,
                                                    const float* __restrict__ w2,
                                                    const float* __restrict__ cvecP,
                                                    const float* __restrict__ merge_b,
                                                    const float* __restrict__ gamma,
                                                    const float* __restrict__ beta,
                                                    float* __restrict__ out) {
    const int g = (blockIdx.x & 7) * 256 + (blockIdx.x >> 3);
    const int wave = threadIdx.x >> 6, lane = threadIdx.x & 63;
    const int row = g * 4 + wave;
    const int t = row & (TT - 1);
    const bf16* Crow = C + (size_t)row * CN;

    const int h0 = lane * 8;
    bf16x8 u8 = *(const bf16x8*)(Crow + h0);
    float4 b1a = *(const float4*)(b1 + h0), b1b = *(const float4*)(b1 + h0 + 4);
    float4 w2a = *(const float4*)(w2 + h0), w2b = *(const float4*)(w2 + h0 + 4);
    float u[8] = {(float)u8[0] + b1a.x, (float)u8[1] + b1a.y,
                  (float)u8[2] + b1a.z, (float)u8[3] + b1a.w,
                  (float)u8[4] + b1b.x, (float)u8[5] + b1b.y,
                  (float)u8[6] + b1b.z, (float)u8[7] + b1b.w};
    const float w2v[8] = {w2a.x, w2a.y, w2a.z, w2a.w, w2b.x, w2b.y, w2b.z, w2b.w};

    float partial[4];
#pragma unroll
    for (int w = 0; w < 4; ++w) {
        float p = 0.f;
        if (t >= w + 1) {
            bf16x8 v8 = *(const bf16x8*)(C + (size_t)(row - w - 1) * CN + 512 + h0);
#pragma unroll
            for (int k = 0; k < 8; ++k) {
                float z = u[k] + (float)v8[k];
                p += (z / (1.f + __expf(-z))) * w2v[k];
            }
        } else {
#pragma unroll
            for (int k = 0; k < 8; ++k) {
                float z = u[k];
                p += (z / (1.f + __expf(-z))) * w2v[k];
            }
        }
        partial[w] = p;
    }
#pragma unroll
    for (int w = 0; w < 4; ++w)
#pragma unroll
        for (int off = 1; off < 64; off <<= 1)
            partial[w] += __shfl_xor(partial[w], off, 64);

    const float bias2 = b2[0];
    float taus[4];
#pragma unroll
    for (int w = 0; w < 4; ++w)
        taus[w] = 1.f / (1.f + __expf(-(partial[w] + bias2)));
    const float tsum = taus[0] + taus[1] + taus[2] + taus[3];

    const int d0 = lane * 16;
    bf16x8 y1a = *(const bf16x8*)(Crow + 2048 + d0);
    bf16x8 y1b = *(const bf16x8*)(Crow + 2048 + d0 + 8);
    float v[16];
#pragma unroll
    for (int k = 0; k < 8; ++k) { v[k] = (float)y1a[k]; v[8 + k] = (float)y1b[k]; }
#pragma unroll
    for (int q = 0; q < 4; ++q) {
        const int d = d0 + q * 4;
        float4 c0 = *(const float4*)(cvecP + d);
        float4 c1 = *(const float4*)(cvecP + 1024 + d);
        float4 c2 = *(const float4*)(cvecP + 2048 + d);
        float4 c3 = *(const float4*)(cvecP + 3072 + d);
        float4 mb = *(const float4*)(merge_b + d);
        v[q*4+0] += tsum * (c0.x + c1.x + c2.x + c3.x) + mb.x;
        v[q*4+1] += tsum * (c0.y + c1.y + c2.y + c3.y) + mb.y;
        v[q*4+2] += tsum * (c0.z + c1.z + c2.z + c3.z) + mb.z;
        v[q*4+3] += tsum * (c0.w + c1.w + c2.w + c3.w) + mb.w;
    }
#pragma unroll
    for (int w = 0; w < 4; ++w) {
        if (t >= w + 1) {
            const bf16* Pn = C + (size_t)(row - w - 1) * CN + 1024 + d0;
            bf16x8 pa = *(const bf16x8*)Pn;
            bf16x8 pb = *(const bf16x8*)(Pn + 8);
#pragma unroll
            for (int k = 0; k < 8; ++k) {
                v[k] += taus[w] * (float)pa[k];
                v[8 + k] += taus[w] * (float)pb[k];
            }
        }
    }

    float s = 0.f, ss = 0.f;
#pragma unroll
    for (int k = 0; k < 16; ++k) { s += v[k]; ss += v[k] * v[k]; }
#pragma unroll
    for (int off = 1; off < 64; off <<= 1) {
        s  += __shfl_xor(s, off, 64);
        ss += __shfl_xor(ss, off, 64);
    }
    const float mu = s * (1.f / TD);
    const float var = ss * (1.f / TD) - mu * mu;
    const float r = rsqrtf(var + EPS);

#pragma unroll
    for (int q = 0; q < 4; ++q) {
        const int d = d0 + q * 4;
        float4 gm = *(const float4*)(gamma + d);
        float4 bt = *(const float4*)(beta + d);
        float4 o;
        o.x = (v[q*4+0] - mu) * r * gm.x + bt.x;
        o.y = (v[q*4+1] - mu) * r * gm.y + bt.y;
        o.z = (v[q*4+2] - mu) * r * gm.z + bt.z;
        o.w = (v[q*4+3] - mu) * r * gm.w + bt.w;
        *(float4*)(out + (size_t)row * TD + d) = o;
    }
}

// ---------------------------------------------------------------------------
extern "C" void kernel_launch(void* const* d_in, const int* in_sizes, int n_in,
                              void* d_out, int out_size, void* d_ws, size_t ws_size,
                              hipStream_t stream) {
    const float* x       = (const float*)d_in[0];
    const float* w1      = (const float*)d_in[1];
    const float* b1      = (const float*)d_in[2];
    const float* w2      = (const float*)d_in[3];
    const float* b2      = (const float*)d_in[4];
    const float* wv_w    = (const float*)d_in[5];
    const float* wv_b    = (const float*)d_in[6];
    const float* merge_w = (const float*)d_in[7];
    const float* merge_b = (const float*)d_in[8];
    const float* gamma   = (const float*)d_in[9];
    const float* beta    = (const float*)d_in[10];
    float* out = (float*)d_out;

    char* ws = (char*)d_ws;
    bf16*  Xbf   = (bf16*)ws;  ws += (size_t)TM * 1024 * 2;    // [8192][1024]
    bf16*  BigBT = (bf16*)ws;  ws += (size_t)CN * 1024 * 2;    // [3072 n][1024 k]
    bf16*  Amb   = (bf16*)ws;  ws += (size_t)1024 * 1024 * 2;  // merge_bot^T
    bf16*  WvBf  = (bf16*)ws;  ws += (size_t)1024 * 1024 * 2;  // wv_w bf16
    float* cvecP = (float*)ws; ws += (size_t)4 * 1024 * 4;     // cvec partials
    bf16*  Cbuf  = (bf16*)ws;                                  // [8192][3072]

    // 1. weights prep (transposes + wv cast)
    prep_kernel<<<4096, 256, 0, stream>>>(w1, wv_w, merge_w, BigBT, Amb, WvBf);

    // 2. wprime GEMM overlapped with x-cast + cvec partials
    aux_kernel<<<8464, 256, 0, stream>>>(x, merge_w, wv_b, Amb, WvBf,
                                         BigBT + (size_t)1024 * 1024, Xbf, cvecP);

    // 3. big GEMM: Cbuf = Xbf @ BigBT^T   (M=8192, N=3072, K=1024)
    gemm_kernel<<<1024, 256, 0, stream>>>(Xbf, BigBT, Cbuf);

    // 4. fused tau + combine + LayerNorm (wave-per-token, XCD token stripes)
    final_kernel<<<2048, 256, 0, stream>>>(Cbuf, b1, b2, w2, cvecP, merge_b,
                                           gamma, beta, out);
}